// Round 4
// baseline (261.496 us; speedup 1.0000x reference)
//
#include <hip/hip_runtime.h>
#include <hip/hip_bf16.h>
#include <stdint.h>

// Self-attention, B=2 T=2048 C=1024 H=16 DH=64, causal + relative bias.
// Round 11: attn64 Q-tile 64 -> 128 rows (4 waves x 32 rows via an added mi
// strip loop). Rationale: LDS-issue-bound (model: ~450 LDS cyc/wave-iter,
// ~49us of 62.8; K/V fragment reads are identical across the 4 waves). Each
// K/V LDS read now feeds 2 MFMAs -> K/V reads, barriers, staging per unit
// work halve. All address maps/swizzles/MFMA/softmax kept byte-identical;
// only the second strip (+64 rows, P rows +16) and a uniform do0 guard for
// the half-masked tail tile are new. 512 blocks (16 tiles x 32 bh), XCD-
// pinned, big-first pairing {15-g, g} (each CU's 2 blocks sum to 34 iters).
// GEMMs verbatim from round 10 (global_load_lds 2-phase, pre-swizzled src).
// Invariants: dual-dtype external loads (flag), ws <= 256B + 22MB.
//
// ws layout (offsets from ws+256, bytes):
//   phase A: WqT @0..2M, WkT @2..4M, WvT @4..6M, K @6..14M, V^T @14..22M
//   phase B (weights/K dead): Y @0..8M, WoT @8..10M
// d_out (16MB): phase A: Q @0..8M, x_bf16 @8..16M; phase B: final f32 out.

#define T_SEQ 2048
#define NH    16
#define DHD   64
#define CDIM  1024

typedef unsigned short u16;
typedef unsigned int   u32;
typedef __attribute__((ext_vector_type(8))) __bf16 bf16x8;   // MFMA A/B operand
typedef __attribute__((ext_vector_type(4))) float f32x4;     // MFMA C/D operand

#define WAITL0   asm volatile("s_waitcnt lgkmcnt(0)" ::: "memory")

__device__ __forceinline__ float bf2f(u16 b){
  union { u32 u; float f; } v; v.u = ((u32)b) << 16; return v.f;
}
__device__ __forceinline__ u16 f2bf(float f){
  union { __bf16 h; u16 u; } v; v.h = (__bf16)f;   // native cvt on gfx950
  return v.u;
}

// async global->LDS, 16B per lane; LDS dest = wave-uniform base + lane*16
__device__ __forceinline__ void gload_lds16(const u16* g, u16* l){
  __builtin_amdgcn_global_load_lds(
      (const __attribute__((address_space(1))) void*)g,
      (__attribute__((address_space(3))) void*)l, 16, 0, 0);
}

// load 8 consecutive elements as packed bf16 (uint4), from bf16 or f32 source
__device__ __forceinline__ uint4 load8(const void* p, long elem, int isbf){
  if (isbf) return *(const uint4*)((const u16*)p + elem);
  const float* fp = (const float*)p + elem;
  float4 a = *(const float4*)fp, b = *(const float4*)(fp + 4);
  uint4 r;
  r.x = (u32)f2bf(a.x) | ((u32)f2bf(a.y) << 16);
  r.y = (u32)f2bf(a.z) | ((u32)f2bf(a.w) << 16);
  r.z = (u32)f2bf(b.x) | ((u32)f2bf(b.y) << 16);
  r.w = (u32)f2bf(b.z) | ((u32)f2bf(b.w) << 16);
  return r;
}
__device__ __forceinline__ float loadf(const void* p, long idx, int isbf){
  return isbf ? bf2f(((const u16*)p)[idx]) : ((const float*)p)[idx];
}

// ---------------- dtype classifier ------------------------------------------
__global__ __launch_bounds__(256) void classify(const u32* __restrict__ x,
                                                int* __restrict__ flag){
  __shared__ int cnt[256];
  int c = 0;
#pragma unroll
  for (int i = 0; i < 16; i++){
    u32 w = x[threadIdx.x * 16 + i];
    int e = (w >> 7) & 0xFF;
    c += (e >= 110 && e <= 140);
  }
  cnt[threadIdx.x] = c;
  __syncthreads();
  for (int s = 128; s > 0; s >>= 1){
    if ((int)threadIdx.x < s) cnt[threadIdx.x] += cnt[threadIdx.x + s];
    __syncthreads();
  }
  if (threadIdx.x == 0) *flag = (cnt[0] > 2048) ? 1 : 0;   // 1 = bf16
}

// ---------------- x -> bf16 (removes per-pass f32 conversion in GEMM) -------
__global__ __launch_bounds__(256) void cvt_x(const void* __restrict__ x,
                                             u16* __restrict__ xbf,
                                             const int* __restrict__ flag){
  const int isbf = *flag;
  const long i = ((long)blockIdx.x * 256 + threadIdx.x) * 8;
  *(uint4*)(xbf + i) = load8(x, i, isbf);
}

// ---------------- weight transpose: out[n][k] = in[k][n], 1024x1024 ----------
__global__ __launch_bounds__(256) void transposeW(
    const void* __restrict__ w0, const void* __restrict__ w1,
    const void* __restrict__ w2,
    u16* __restrict__ o0, u16* __restrict__ o1, u16* __restrict__ o2,
    const int* __restrict__ flag)
{
  __shared__ u16 tile[64][72];
  const int isbf = *flag;
  const int z = blockIdx.z;
  const void* in = z==0 ? w0 : z==1 ? w1 : w2;
  u16*      out  = z==0 ? o0 : z==1 ? o1 : o2;
  const int tid = threadIdx.x;
  const int r0 = blockIdx.y * 64, c0 = blockIdx.x * 64;
  const int rr = tid >> 3;          // 0..31
  const int cc = (tid & 7) * 8;     // 0,8,..,56
#pragma unroll
  for (int rd = 0; rd < 2; rd++){
    int r = rd*32 + rr;
    *(uint4*)&tile[r][cc] = load8(in, (long)(r0 + r)*CDIM + c0 + cc, isbf);
  }
  __syncthreads();
#pragma unroll
  for (int rd = 0; rd < 2; rd++){
    int oc = rd*32 + rr;            // original column offset
    uint4 wv; u32* wp = (u32*)&wv;
#pragma unroll
    for (int t = 0; t < 4; t++){
      u32 lo = tile[cc + 2*t][oc];
      u32 hi = tile[cc + 2*t + 1][oc];
      wp[t] = lo | (hi << 16);
    }
    *(uint4*)(out + (long)(c0 + oc)*CDIM + r0 + cc) = wv;
  }
}

// ---------------- 128x128 GEMM, global_load_lds 2-phase K-loop --------------
// A[M,K] (bf16) @ BT[N,K]^T, K=1024, BK=32, double-buffered 16KB LDS/operand.
// Staging: chunk c = wid*128 + s*64 + lane; LDS slot g'=c&3 of row r=c>>2
// receives SOURCE chunk g'^(r&3) (pre-swizzled source address) -> identical
// LDS image to the old swizzled ds_write path; read side unchanged.
// mode 0: out[m*CDIM+n] + bias (dtype per io_isbf)
// mode 1: out[((b*NH+h)*T+t)*DH+d] bf16 (Q/K; scale applied)
// mode 2: out[((b*NH+h)*DH+d)*T+t] bf16 (V transposed; 8B packed stores)
__device__ __forceinline__ void gemm_body(
    const u16* __restrict__ A, const u16* __restrict__ BT,
    const void* __restrict__ bias, void* __restrict__ out,
    float scale, int mode, int m0, int n0, int io_isbf)
{
  __shared__ u16 ldsA[2][128*32];
  __shared__ u16 ldsB[2][128*32];
  const int tid = threadIdx.x;
  const int wid = tid >> 6, lane = tid & 63;
  const int col = lane & 15, quad = lane >> 4;
  const int wm = (wid >> 1) * 64, wn = (wid & 1) * 64;

  // per-lane pre-swizzled source offsets for the two 64-chunk instructions
  const int c0 = wid*128 + lane, c1 = c0 + 64;
  const int r0c = c0 >> 2, g0c = c0 & 3;
  const int r1c = c1 >> 2, g1c = c1 & 3;
  const long aoff0 = (long)r0c*CDIM + ((g0c ^ (r0c & 3)) << 3);
  const long aoff1 = (long)r1c*CDIM + ((g1c ^ (r1c & 3)) << 3);
  const int lds0 = (wid*128)*8;          // u16 elems; HW adds lane*16B
  const int lds1 = (wid*128 + 64)*8;

  const u16* gA = A  + (long)m0*CDIM;
  const u16* gB = BT + (long)n0*CDIM;

  auto stage = [&](int buf, int k0){
    gload_lds16(gA + k0 + aoff0, &ldsA[buf][lds0]);
    gload_lds16(gA + k0 + aoff1, &ldsA[buf][lds1]);
    gload_lds16(gB + k0 + aoff0, &ldsB[buf][lds0]);
    gload_lds16(gB + k0 + aoff1, &ldsB[buf][lds1]);
  };

  f32x4 acc[4][4] = {};
  const int NK = CDIM / 32;

  stage(0, 0);
  __syncthreads();            // vmcnt(0) drain: tile 0 visible

  int cur = 0;
  for (int k = 0; k < NK; k++){
    if (k + 1 < NK) stage(cur ^ 1, (k + 1) * 32);   // async into other buffer

    bf16x8 af[4], bfr[4];
#pragma unroll
    for (int mi = 0; mi < 4; mi++){
      const int r = wm + mi*16 + col;
      af[mi] = *(const bf16x8*)&ldsA[cur][r*32 + ((quad ^ (r & 3)) * 8)];
    }
#pragma unroll
    for (int ni = 0; ni < 4; ni++){
      const int r = wn + ni*16 + col;
      bfr[ni] = *(const bf16x8*)&ldsB[cur][r*32 + ((quad ^ (r & 3)) * 8)];
    }
#pragma unroll
    for (int mi = 0; mi < 4; mi++)
#pragma unroll
      for (int ni = 0; ni < 4; ni++)
        acc[mi][ni] = __builtin_amdgcn_mfma_f32_16x16x32_bf16(af[mi], bfr[ni], acc[mi][ni], 0, 0, 0);

    __syncthreads();          // readers done with cur; next tile landed
    cur ^= 1;
  }

  // epilogue
  if (mode == 2){
#pragma unroll
    for (int ni = 0; ni < 4; ni++){
      const int n = n0 + wn + ni*16 + col;
      const int h = n >> 6, d = n & 63;
#pragma unroll
      for (int mi = 0; mi < 4; mi++){
        const int m = m0 + wm + mi*16 + quad*4;
        const int b = m >> 11, t = m & (T_SEQ-1);
        uint2 pk;
        pk.x = (u32)f2bf(acc[mi][ni][0]) | ((u32)f2bf(acc[mi][ni][1]) << 16);
        pk.y = (u32)f2bf(acc[mi][ni][2]) | ((u32)f2bf(acc[mi][ni][3]) << 16);
        *(uint2*)((u16*)out + ((long)(b*NH + h)*DHD + d)*T_SEQ + t) = pk;
      }
    }
  } else {
#pragma unroll
    for (int ni = 0; ni < 4; ni++){
      const int n = n0 + wn + ni*16 + col;
      const float bv = bias ? loadf(bias, n, io_isbf) : 0.f;
#pragma unroll
      for (int mi = 0; mi < 4; mi++){
#pragma unroll
        for (int r = 0; r < 4; r++){
          const int m = m0 + wm + mi*16 + quad*4 + r;
          const float v = acc[mi][ni][r] * scale + bv;
          if (mode == 0){
            const long idx = (long)m*CDIM + n;
            if (io_isbf) ((u16*)out)[idx] = f2bf(v);
            else         ((float*)out)[idx] = v;
          } else {
            const int b = m >> 11, t = m & (T_SEQ-1), h = n >> 6, d = n & 63;
            ((u16*)out)[((long)(b*NH + h)*T_SEQ + t)*DHD + d] = f2bf(v);
          }
        }
      }
    }
  }
}

__global__ __launch_bounds__(256) void gemm_qkv(
    const u16* __restrict__ xbf,
    const u16* __restrict__ WqT, const u16* __restrict__ WkT, const u16* __restrict__ WvT,
    u16* __restrict__ Qb, u16* __restrict__ Kb, u16* __restrict__ VTb)
{
  const int z = blockIdx.z;
  const u16* BT = z==0 ? WqT : z==1 ? WkT : WvT;
  u16*      dst = z==0 ? Qb  : z==1 ? Kb  : VTb;
  // Q: fold DH^-0.5 and log2(e) so attention exp is a bare v_exp_f32
  const float scale = (z==0) ? 0.125f * 1.44269504f : 1.0f;
  const int mode = (z==2) ? 2 : 1;
  gemm_body(xbf, BT, nullptr, dst, scale, mode, blockIdx.x*128, blockIdx.y*128, 1);
}

__global__ __launch_bounds__(256) void gemm_out(
    const u16* __restrict__ Y, const u16* __restrict__ WoT,
    const void* __restrict__ bo, void* __restrict__ out,
    const int* __restrict__ flag)
{
  gemm_body(Y, WoT, bo, out, 1.0f, 0, blockIdx.x*128, blockIdx.y*128, *flag);
}

// ---------------- flash attention, 128-row Q-tile, 4 waves x 32 rows --------
// 512 blocks = 8 XCDs x 4 heads x 16 tiles. xcd = l&7 owns heads
// [xcd*4, xcd*4+4) so each XCD's K/V working set is 2MB (fits 4MB L2).
// Each wave owns two 16-row strips (mi = 0,1 at +0/+64): every K/V LDS
// fragment read feeds 2 MFMAs -> K/V reads, barriers, staging per unit work
// halve vs round 10 (LDS-issue-bound per cycle model). Tail tile j0 = i0+64
// is strip-1-only (do0 guard, uniform branch). Pairing {15-g, g}: each CU's
// 2 blocks sum to 34 KV-iters; big tiles dispatch first.
__global__ __launch_bounds__(256, 2) void attn64(
    const u16* __restrict__ Q, const u16* __restrict__ K, const u16* __restrict__ VT,
    const void* __restrict__ rel, u16* __restrict__ Y,
    const int* __restrict__ flag)
{
  __shared__ u16 ldsK[64*64];
  __shared__ u16 ldsV[64*64];
  __shared__ u16 ldsP[4][32*88];    // per-wave P (32 rows), row stride 88
  __shared__ float ldsBias[2112];   // biasL[d+63], d = i-j

  const int isbf = *flag;
  const int tid = threadIdx.x, wid = tid >> 6, lane = tid & 63;
  const int col = lane & 15, quad = lane >> 4;

  // XCD-aware decode: l&7 = xcd, s = l>>3 in [0,64); bh = xcd*4 + (s&3);
  // g = s>>2 in [0,16) -> ti: big-first halves {15..8} then {0..7}.
  const int l = (int)blockIdx.x;
  const int xcd = l & 7, s = l >> 3;
  const int bh = xcd * 4 + (s & 3);
  const int g = s >> 2;
  const int ti = (g < 8) ? (15 - g) : (g - 8);
  const int i0 = ti * 128;

  const int h = bh & (NH - 1);
  const int b = bh >> 4;

  const u16* Qh = Q  + (long)bh * T_SEQ * DHD;
  const u16* Kh = K  + (long)bh * T_SEQ * DHD;
  const u16* Vh = VT + (long)bh * DHD * T_SEQ;
  const long relbase = (long)h * (2*T_SEQ - 1) + (T_SEQ - 1);
  const float MLOG = 16.0f * 1.44269504f;

  // staging map: thread covers chunks c = tid, tid+256 (row=c>>3, slot=c&7)
  const int kr0 = tid >> 3, ks = tid & 7;
  const int kr1 = kr0 + 32;
  const int kd0 = (ks ^ (kr0 & 7)) * 8;
  const int kd1 = (ks ^ (kr1 & 7)) * 8;

  uint4 rk0, rk1, rv0, rv1;
  auto loadKV = [&](int j0){
    rk0 = *(const uint4*)(Kh + (long)(j0 + kr0)*DHD + ks*8);
    rk1 = *(const uint4*)(Kh + (long)(j0 + kr1)*DHD + ks*8);
    rv0 = *(const uint4*)(Vh + (long)kr0*T_SEQ + j0 + ks*8);
    rv1 = *(const uint4*)(Vh + (long)kr1*T_SEQ + j0 + ks*8);
  };
  auto storeKV = [&](){
    *(uint4*)&ldsK[kr0*64 + kd0] = rk0;
    *(uint4*)&ldsK[kr1*64 + kd1] = rk1;
    *(uint4*)&ldsV[kr0*64 + kd0] = rv0;
    *(uint4*)&ldsV[kr1*64 + kd1] = rv1;
  };

  // stage biasL for d in [-63, i0+127]
  const int nbias = i0 + 191;
  for (int t = tid; t < nbias; t += 256)
    ldsBias[t] = loadf(rel, relbase + t - 63, isbf) * 1.44269504f - MLOG;

  // A-operand Q for both strips: row i0 + mi*64 + wid*16 + col
  bf16x8 qf[2][2];
#pragma unroll
  for (int mi = 0; mi < 2; mi++){
    const u16* qp = Qh + (long)(i0 + mi*64 + wid*16 + col)*DHD + quad*8;
    qf[mi][0] = *(const bf16x8*)qp;
    qf[mi][1] = *(const bf16x8*)(qp + 32);
  }

  f32x4 O0[4] = {}, O1[4] = {};
  float lsum0[4] = {0.f,0.f,0.f,0.f}, lsum1[4] = {0.f,0.f,0.f,0.f};
  const int irow0 = i0 + wid*16 + quad*4;
  const int irow1 = irow0 + 64;

  loadKV(0);
  storeKV();
  __syncthreads();   // KV tile + bias visible

  for (int j0 = 0; j0 <= i0 + 64; j0 += 64){
    const bool do0 = (j0 <= i0);          // strip 0 active; also == have_next
    if (do0) loadKV(j0 + 64);             // loads fly during compute

    // S = Q K^T (shared kf feeds both strips)
    f32x4 s0[4] = {}, s1[4] = {};
#pragma unroll
    for (int kb = 0; kb < 2; kb++){
#pragma unroll
      for (int nb = 0; nb < 4; nb++){
        const int row = nb*16 + col;
        const int sl = ((kb*4 + quad) ^ (row & 7)) * 8;
        bf16x8 kf = *(const bf16x8*)&ldsK[row*64 + sl];
        if (do0) s0[nb] = __builtin_amdgcn_mfma_f32_16x16x32_bf16(qf[0][kb], kf, s0[nb], 0, 0, 0);
        s1[nb] = __builtin_amdgcn_mfma_f32_16x16x32_bf16(qf[1][kb], kf, s1[nb], 0, 0, 0);
      }
    }

    // p = exp2(s + biasL); per-lane row sums
    const bool diag0 = (j0 == i0);
    const bool diag1 = (j0 == i0 + 64);
    if (do0){
#pragma unroll
      for (int nb = 0; nb < 4; nb++){
        const int j = j0 + nb*16 + col;
        const float* bp = &ldsBias[irow0 - j + 63];
#pragma unroll
        for (int r = 0; r < 4; r++){
          float arg = s0[nb][r] + bp[r];
          if (diag0 && (j > irow0 + r)) arg = -1e9f;
          float p;
          asm volatile("v_exp_f32 %0, %1" : "=v"(p) : "v"(arg));
          s0[nb][r] = p;
          lsum0[r] += p;
        }
      }
    }
#pragma unroll
    for (int nb = 0; nb < 4; nb++){
      const int j = j0 + nb*16 + col;
      const float* bp = &ldsBias[irow1 - j + 63];
#pragma unroll
      for (int r = 0; r < 4; r++){
        float arg = s1[nb][r] + bp[r];
        if (diag1 && (j > irow1 + r)) arg = -1e9f;
        float p;
        asm volatile("v_exp_f32 %0, %1" : "=v"(p) : "v"(arg));
        s1[nb][r] = p;
        lsum1[r] += p;
      }
    }

    // P: C-layout -> per-wave LDS -> A-layout (strip mi at row offset mi*16)
    u16* Pw = ldsP[wid];
    if (do0){
#pragma unroll
      for (int nb = 0; nb < 4; nb++)
#pragma unroll
        for (int r = 0; r < 4; r++)
          Pw[(quad*4 + r)*88 + nb*16 + col] = f2bf(s0[nb][r]);
    }
#pragma unroll
    for (int nb = 0; nb < 4; nb++)
#pragma unroll
      for (int r = 0; r < 4; r++)
        Pw[(16 + quad*4 + r)*88 + nb*16 + col] = f2bf(s1[nb][r]);
    WAITL0;

    // O += P V (shared vf feeds both strips)
#pragma unroll
    for (int kb = 0; kb < 2; kb++){
      bf16x8 pf0 = *(const bf16x8*)&Pw[col*88 + kb*32 + quad*8];
      bf16x8 pf1 = *(const bf16x8*)&Pw[(16 + col)*88 + kb*32 + quad*8];
#pragma unroll
      for (int nb = 0; nb < 4; nb++){
        const int row = nb*16 + col;
        const int sl = ((kb*4 + quad) ^ (row & 7)) * 8;
        bf16x8 vf = *(const bf16x8*)&ldsV[row*64 + sl];
        if (do0) O0[nb] = __builtin_amdgcn_mfma_f32_16x16x32_bf16(pf0, vf, O0[nb], 0, 0, 0);
        O1[nb] = __builtin_amdgcn_mfma_f32_16x16x32_bf16(pf1, vf, O1[nb], 0, 0, 0);
      }
    }

    __syncthreads();                 // all waves done reading K/V
    if (do0){
      storeKV();                     // prefetched tile -> LDS
      __syncthreads();
    }
  }

  // reduce row sums across the 16 cols of each quad (both strips)
#pragma unroll
  for (int r = 0; r < 4; r++){
    float v = lsum0[r];
    v += __shfl_xor(v, 1, 64);
    v += __shfl_xor(v, 2, 64);
    v += __shfl_xor(v, 4, 64);
    v += __shfl_xor(v, 8, 64);
    lsum0[r] = v;
    float w = lsum1[r];
    w += __shfl_xor(w, 1, 64);
    w += __shfl_xor(w, 2, 64);
    w += __shfl_xor(w, 4, 64);
    w += __shfl_xor(w, 8, 64);
    lsum1[r] = w;
  }

  // epilogue: O/l -> Y[(b*T + i)*C + h*64 + d], both strips
#pragma unroll
  for (int nb = 0; nb < 4; nb++){
#pragma unroll
    for (int r = 0; r < 4; r++){
      const int d = nb*16 + col;
      Y[((long)(b*T_SEQ + irow0 + r))*CDIM + h*DHD + d] = f2bf(O0[nb][r] / lsum0[r]);
      Y[((long)(b*T_SEQ + irow1 + r))*CDIM + h*DHD + d] = f2bf(O1[nb][r] / lsum1[r]);
    }
  }
}

extern "C" void kernel_launch(void* const* d_in, const int* in_sizes, int n_in,
                              void* d_out, int out_size, void* d_ws, size_t ws_size,
                              hipStream_t stream)
{
  (void)in_sizes; (void)n_in; (void)out_size; (void)ws_size;
  const void* x   = d_in[0];
  const void* Wq  = d_in[1];
  const void* Wk  = d_in[2];
  const void* Wv  = d_in[3];
  const void* Wo  = d_in[4];
  const void* bo  = d_in[5];
  const void* rel = d_in[6];
  // d_in[7] = mask: deterministically causal -> not read

  char* ws = (char*)d_ws;
  const size_t MB = 1024*1024;
  int* flag = (int*)ws;
  char* base = ws + 256;
  u16* WqT = (u16*)(base + 0*MB);
  u16* WkT = (u16*)(base + 2*MB);
  u16* WvT = (u16*)(base + 4*MB);
  u16* Kb  = (u16*)(base + 6*MB);
  u16* VTb = (u16*)(base + 14*MB);    // ..22MB
  u16* Yb  = (u16*)(base + 0*MB);     // phase B: overlaps dead WqT/WkT/WvT
  u16* WoT = (u16*)(base + 8*MB);     // phase B: overlaps dead Kb
  u16* Qb  = (u16*)d_out;             // d_out lower 8MB: Q (overwritten later)
  u16* xbf = Qb + 4u*1024*1024;       // d_out upper 8MB: x as bf16

  dim3 blk(256);
  classify  <<<1, blk, 0, stream>>>((const u32*)x, flag);
  cvt_x     <<<dim3(2048), blk, 0, stream>>>(x, xbf, flag);
  transposeW<<<dim3(16,16,3), blk, 0, stream>>>(Wq, Wk, Wv, WqT, WkT, WvT, flag);
  gemm_qkv  <<<dim3(32,8,3),  blk, 0, stream>>>(xbf, WqT, WkT, WvT, Qb, Kb, VTb);
  attn64    <<<dim3(512),  blk, 0, stream>>>(Qb, Kb, VTb, rel, Yb, flag);
  transposeW<<<dim3(16,16,1), blk, 0, stream>>>(Wo, Wo, Wo, WoT, WoT, WoT, flag);
  gemm_out  <<<dim3(32,8),    blk, 0, stream>>>(Yb, WoT, bo, d_out, flag);
}

// Round 5
// 221.445 us; speedup vs baseline: 1.1809x; 1.1809x over previous
//
#include <hip/hip_runtime.h>
#include <hip/hip_bf16.h>
#include <stdint.h>

// Self-attention, B=2 T=2048 C=1024 H=16 DH=64, causal + relative bias.
// Round 12: attn64 reverted to the round-10 body/decomposition (1024 blocks,
// 64-row tiles, balanced quartets; round-11's 128-row rewrite collapsed
// occupancy and regressed). Single change: K/V staging is now async
// global_load_lds into a DOUBLE buffer with pre-swizzled source addresses
// (same involution as the GEMM staging, verified round 10). Removes 4
// ds_write_b128 + one barrier per iter + staging VGPRs/addr-VALU; LDS image
// and the entire read/softmax/PV/epilogue side are byte-identical. LDS 52.5KB
// -> 3 blocks/CU (measured R9->R10: 4 vs 2 blocks was only +5%, so -1 block
// costs ~2%; barrier/staging removal should net positive).
// GEMMs verbatim from round 10 (global_load_lds 2-phase, pre-swizzled src).
// Invariants: dual-dtype external loads (flag), ws <= 256B + 22MB.
//
// ws layout (offsets from ws+256, bytes):
//   phase A: WqT @0..2M, WkT @2..4M, WvT @4..6M, K @6..14M, V^T @14..22M
//   phase B (weights/K dead): Y @0..8M, WoT @8..10M
// d_out (16MB): phase A: Q @0..8M, x_bf16 @8..16M; phase B: final f32 out.

#define T_SEQ 2048
#define NH    16
#define DHD   64
#define CDIM  1024

typedef unsigned short u16;
typedef unsigned int   u32;
typedef __attribute__((ext_vector_type(8))) __bf16 bf16x8;   // MFMA A/B operand
typedef __attribute__((ext_vector_type(4))) float f32x4;     // MFMA C/D operand

#define WAITL0   asm volatile("s_waitcnt lgkmcnt(0)" ::: "memory")

__device__ __forceinline__ float bf2f(u16 b){
  union { u32 u; float f; } v; v.u = ((u32)b) << 16; return v.f;
}
__device__ __forceinline__ u16 f2bf(float f){
  union { __bf16 h; u16 u; } v; v.h = (__bf16)f;   // native cvt on gfx950
  return v.u;
}

// async global->LDS, 16B per lane; LDS dest = wave-uniform base + lane*16
__device__ __forceinline__ void gload_lds16(const u16* g, u16* l){
  __builtin_amdgcn_global_load_lds(
      (const __attribute__((address_space(1))) void*)g,
      (__attribute__((address_space(3))) void*)l, 16, 0, 0);
}

// load 8 consecutive elements as packed bf16 (uint4), from bf16 or f32 source
__device__ __forceinline__ uint4 load8(const void* p, long elem, int isbf){
  if (isbf) return *(const uint4*)((const u16*)p + elem);
  const float* fp = (const float*)p + elem;
  float4 a = *(const float4*)fp, b = *(const float4*)(fp + 4);
  uint4 r;
  r.x = (u32)f2bf(a.x) | ((u32)f2bf(a.y) << 16);
  r.y = (u32)f2bf(a.z) | ((u32)f2bf(a.w) << 16);
  r.z = (u32)f2bf(b.x) | ((u32)f2bf(b.y) << 16);
  r.w = (u32)f2bf(b.z) | ((u32)f2bf(b.w) << 16);
  return r;
}
__device__ __forceinline__ float loadf(const void* p, long idx, int isbf){
  return isbf ? bf2f(((const u16*)p)[idx]) : ((const float*)p)[idx];
}

// ---------------- dtype classifier ------------------------------------------
__global__ __launch_bounds__(256) void classify(const u32* __restrict__ x,
                                                int* __restrict__ flag){
  __shared__ int cnt[256];
  int c = 0;
#pragma unroll
  for (int i = 0; i < 16; i++){
    u32 w = x[threadIdx.x * 16 + i];
    int e = (w >> 7) & 0xFF;
    c += (e >= 110 && e <= 140);
  }
  cnt[threadIdx.x] = c;
  __syncthreads();
  for (int s = 128; s > 0; s >>= 1){
    if ((int)threadIdx.x < s) cnt[threadIdx.x] += cnt[threadIdx.x + s];
    __syncthreads();
  }
  if (threadIdx.x == 0) *flag = (cnt[0] > 2048) ? 1 : 0;   // 1 = bf16
}

// ---------------- x -> bf16 (removes per-pass f32 conversion in GEMM) -------
__global__ __launch_bounds__(256) void cvt_x(const void* __restrict__ x,
                                             u16* __restrict__ xbf,
                                             const int* __restrict__ flag){
  const int isbf = *flag;
  const long i = ((long)blockIdx.x * 256 + threadIdx.x) * 8;
  *(uint4*)(xbf + i) = load8(x, i, isbf);
}

// ---------------- weight transpose: out[n][k] = in[k][n], 1024x1024 ----------
__global__ __launch_bounds__(256) void transposeW(
    const void* __restrict__ w0, const void* __restrict__ w1,
    const void* __restrict__ w2,
    u16* __restrict__ o0, u16* __restrict__ o1, u16* __restrict__ o2,
    const int* __restrict__ flag)
{
  __shared__ u16 tile[64][72];
  const int isbf = *flag;
  const int z = blockIdx.z;
  const void* in = z==0 ? w0 : z==1 ? w1 : w2;
  u16*      out  = z==0 ? o0 : z==1 ? o1 : o2;
  const int tid = threadIdx.x;
  const int r0 = blockIdx.y * 64, c0 = blockIdx.x * 64;
  const int rr = tid >> 3;          // 0..31
  const int cc = (tid & 7) * 8;     // 0,8,..,56
#pragma unroll
  for (int rd = 0; rd < 2; rd++){
    int r = rd*32 + rr;
    *(uint4*)&tile[r][cc] = load8(in, (long)(r0 + r)*CDIM + c0 + cc, isbf);
  }
  __syncthreads();
#pragma unroll
  for (int rd = 0; rd < 2; rd++){
    int oc = rd*32 + rr;            // original column offset
    uint4 wv; u32* wp = (u32*)&wv;
#pragma unroll
    for (int t = 0; t < 4; t++){
      u32 lo = tile[cc + 2*t][oc];
      u32 hi = tile[cc + 2*t + 1][oc];
      wp[t] = lo | (hi << 16);
    }
    *(uint4*)(out + (long)(c0 + oc)*CDIM + r0 + cc) = wv;
  }
}

// ---------------- 128x128 GEMM, global_load_lds 2-phase K-loop --------------
// A[M,K] (bf16) @ BT[N,K]^T, K=1024, BK=32, double-buffered 16KB LDS/operand.
// Staging: chunk c = wid*128 + s*64 + lane; LDS slot g'=c&3 of row r=c>>2
// receives SOURCE chunk g'^(r&3) (pre-swizzled source address) -> identical
// LDS image to the old swizzled ds_write path; read side unchanged.
// mode 0: out[m*CDIM+n] + bias (dtype per io_isbf)
// mode 1: out[((b*NH+h)*T+t)*DH+d] bf16 (Q/K; scale applied)
// mode 2: out[((b*NH+h)*DH+d)*T+t] bf16 (V transposed; 8B packed stores)
__device__ __forceinline__ void gemm_body(
    const u16* __restrict__ A, const u16* __restrict__ BT,
    const void* __restrict__ bias, void* __restrict__ out,
    float scale, int mode, int m0, int n0, int io_isbf)
{
  __shared__ u16 ldsA[2][128*32];
  __shared__ u16 ldsB[2][128*32];
  const int tid = threadIdx.x;
  const int wid = tid >> 6, lane = tid & 63;
  const int col = lane & 15, quad = lane >> 4;
  const int wm = (wid >> 1) * 64, wn = (wid & 1) * 64;

  // per-lane pre-swizzled source offsets for the two 64-chunk instructions
  const int c0 = wid*128 + lane, c1 = c0 + 64;
  const int r0c = c0 >> 2, g0c = c0 & 3;
  const int r1c = c1 >> 2, g1c = c1 & 3;
  const long aoff0 = (long)r0c*CDIM + ((g0c ^ (r0c & 3)) << 3);
  const long aoff1 = (long)r1c*CDIM + ((g1c ^ (r1c & 3)) << 3);
  const int lds0 = (wid*128)*8;          // u16 elems; HW adds lane*16B
  const int lds1 = (wid*128 + 64)*8;

  const u16* gA = A  + (long)m0*CDIM;
  const u16* gB = BT + (long)n0*CDIM;

  auto stage = [&](int buf, int k0){
    gload_lds16(gA + k0 + aoff0, &ldsA[buf][lds0]);
    gload_lds16(gA + k0 + aoff1, &ldsA[buf][lds1]);
    gload_lds16(gB + k0 + aoff0, &ldsB[buf][lds0]);
    gload_lds16(gB + k0 + aoff1, &ldsB[buf][lds1]);
  };

  f32x4 acc[4][4] = {};
  const int NK = CDIM / 32;

  stage(0, 0);
  __syncthreads();            // vmcnt(0) drain: tile 0 visible

  int cur = 0;
  for (int k = 0; k < NK; k++){
    if (k + 1 < NK) stage(cur ^ 1, (k + 1) * 32);   // async into other buffer

    bf16x8 af[4], bfr[4];
#pragma unroll
    for (int mi = 0; mi < 4; mi++){
      const int r = wm + mi*16 + col;
      af[mi] = *(const bf16x8*)&ldsA[cur][r*32 + ((quad ^ (r & 3)) * 8)];
    }
#pragma unroll
    for (int ni = 0; ni < 4; ni++){
      const int r = wn + ni*16 + col;
      bfr[ni] = *(const bf16x8*)&ldsB[cur][r*32 + ((quad ^ (r & 3)) * 8)];
    }
#pragma unroll
    for (int mi = 0; mi < 4; mi++)
#pragma unroll
      for (int ni = 0; ni < 4; ni++)
        acc[mi][ni] = __builtin_amdgcn_mfma_f32_16x16x32_bf16(af[mi], bfr[ni], acc[mi][ni], 0, 0, 0);

    __syncthreads();          // readers done with cur; next tile landed
    cur ^= 1;
  }

  // epilogue
  if (mode == 2){
#pragma unroll
    for (int ni = 0; ni < 4; ni++){
      const int n = n0 + wn + ni*16 + col;
      const int h = n >> 6, d = n & 63;
#pragma unroll
      for (int mi = 0; mi < 4; mi++){
        const int m = m0 + wm + mi*16 + quad*4;
        const int b = m >> 11, t = m & (T_SEQ-1);
        uint2 pk;
        pk.x = (u32)f2bf(acc[mi][ni][0]) | ((u32)f2bf(acc[mi][ni][1]) << 16);
        pk.y = (u32)f2bf(acc[mi][ni][2]) | ((u32)f2bf(acc[mi][ni][3]) << 16);
        *(uint2*)((u16*)out + ((long)(b*NH + h)*DHD + d)*T_SEQ + t) = pk;
      }
    }
  } else {
#pragma unroll
    for (int ni = 0; ni < 4; ni++){
      const int n = n0 + wn + ni*16 + col;
      const float bv = bias ? loadf(bias, n, io_isbf) : 0.f;
#pragma unroll
      for (int mi = 0; mi < 4; mi++){
#pragma unroll
        for (int r = 0; r < 4; r++){
          const int m = m0 + wm + mi*16 + quad*4 + r;
          const float v = acc[mi][ni][r] * scale + bv;
          if (mode == 0){
            const long idx = (long)m*CDIM + n;
            if (io_isbf) ((u16*)out)[idx] = f2bf(v);
            else         ((float*)out)[idx] = v;
          } else {
            const int b = m >> 11, t = m & (T_SEQ-1), h = n >> 6, d = n & 63;
            ((u16*)out)[((long)(b*NH + h)*T_SEQ + t)*DHD + d] = f2bf(v);
          }
        }
      }
    }
  }
}

__global__ __launch_bounds__(256) void gemm_qkv(
    const u16* __restrict__ xbf,
    const u16* __restrict__ WqT, const u16* __restrict__ WkT, const u16* __restrict__ WvT,
    u16* __restrict__ Qb, u16* __restrict__ Kb, u16* __restrict__ VTb)
{
  const int z = blockIdx.z;
  const u16* BT = z==0 ? WqT : z==1 ? WkT : WvT;
  u16*      dst = z==0 ? Qb  : z==1 ? Kb  : VTb;
  // Q: fold DH^-0.5 and log2(e) so attention exp is a bare v_exp_f32
  const float scale = (z==0) ? 0.125f * 1.44269504f : 1.0f;
  const int mode = (z==2) ? 2 : 1;
  gemm_body(xbf, BT, nullptr, dst, scale, mode, blockIdx.x*128, blockIdx.y*128, 1);
}

__global__ __launch_bounds__(256) void gemm_out(
    const u16* __restrict__ Y, const u16* __restrict__ WoT,
    const void* __restrict__ bo, void* __restrict__ out,
    const int* __restrict__ flag)
{
  gemm_body(Y, WoT, bo, out, 1.0f, 0, blockIdx.x*128, blockIdx.y*128, *flag);
}

// ---------------- flash attention, one 64-row Q-tile per block --------------
// 1024 blocks = 8 XCDs x 4 heads x 32 tiles. xcd = l&7 owns heads
// [xcd*4, xcd*4+4) so each XCD's K/V working set is 2MB (fits 4MB L2).
// ti permuted into balanced quartets. K/V staged via async global_load_lds
// into a double buffer (pre-swizzled source; LDS image identical to the old
// ds_write path) -> ONE barrier per iter, no staging registers/ds_writes.
// Read side / softmax / P bounce / epilogue = round-10 verified code.
__global__ __launch_bounds__(256) void attn64(
    const u16* __restrict__ Q, const u16* __restrict__ K, const u16* __restrict__ VT,
    const void* __restrict__ rel, u16* __restrict__ Y,
    const int* __restrict__ flag)
{
  __shared__ u16 ldsK[2][64*64];
  __shared__ u16 ldsV[2][64*64];
  __shared__ u16 ldsP[4][16*88];    // per-wave P, row stride 88
  __shared__ float ldsBias[2112];   // biasL[d+63], d = i-j

  const int isbf = *flag;
  const int tid = threadIdx.x, wid = tid >> 6, lane = tid & 63;
  const int col = lane & 15, quad = lane >> 4;

  const int l = (int)blockIdx.x;
  const int xcd = l & 7, s = l >> 3;        // s in [0,128)
  const int bh = xcd * 4 + (s & 3);
  const int g = s >> 2, gq = g >> 3, g0 = g & 7;   // g in [0,32)
  const int ti = (gq == 0) ? 31 - g0
               : (gq == 1) ? g0
               : (gq == 2) ? 23 - g0
                           : 8 + g0;
  const int i0 = ti * 64;

  const int h = bh & (NH - 1);
  const int b = bh >> 4;

  const u16* Qh = Q  + (long)bh * T_SEQ * DHD;
  const u16* Kh = K  + (long)bh * T_SEQ * DHD;
  const u16* Vh = VT + (long)bh * DHD * T_SEQ;
  const long relbase = (long)h * (2*T_SEQ - 1) + (T_SEQ - 1);
  const float MLOG = 16.0f * 1.44269504f;

  // async staging map: wave w covers chunks c = w*64+lane and 256 + w*64+lane
  // (row = c>>3, slot = c&7); source chunk = slot^(row&7) (involution), so
  // the LDS image matches the old swizzled ds_write path exactly.
  const int srow0 = wid*8 + (lane >> 3);          // rows 0..31
  const int srow1 = srow0 + 32;                   // rows 32..63
  const int soff  = ((lane & 7) ^ ((lane >> 3) & 7)) * 8;  // swizzled src col
  const int sb0   = wid*512;                      // u16; HW adds lane*16B
  const int sb1   = 2048 + wid*512;

  auto stage = [&](int buf, int j0){
    gload_lds16(Kh + (long)(j0 + srow0)*DHD + soff, &ldsK[buf][sb0]);
    gload_lds16(Kh + (long)(j0 + srow1)*DHD + soff, &ldsK[buf][sb1]);
    gload_lds16(Vh + (long)srow0*T_SEQ + j0 + soff, &ldsV[buf][sb0]);
    gload_lds16(Vh + (long)srow1*T_SEQ + j0 + soff, &ldsV[buf][sb1]);
  };

  // stage biasL for d in [-63, i0+63]
  const int nbias = i0 + 127;
  for (int t = tid; t < nbias; t += 256)
    ldsBias[t] = loadf(rel, relbase + t - 63, isbf) * 1.44269504f - MLOG;

  bf16x8 qf0, qf1;   // A-operand: row i0+wid*16+col, k = kb*32+quad*8+j
  {
    const u16* qp = Qh + (long)(i0 + wid*16 + col)*DHD + quad*8;
    qf0 = *(const bf16x8*)qp;
    qf1 = *(const bf16x8*)(qp + 32);
  }

  f32x4 O[4] = {};
  float lsum[4] = {0.f, 0.f, 0.f, 0.f};
  const int irow = i0 + wid*16 + quad*4;

  stage(0, 0);
  __syncthreads();   // vmcnt+lgkm drain: KV tile 0 + bias visible

  int cur = 0;
  for (int j0 = 0; j0 <= i0; j0 += 64){
    const bool have_next = (j0 + 64 <= i0);
    if (have_next) stage(cur ^ 1, j0 + 64);   // async into other buffer

    // S = Q K^T
    f32x4 s[4] = {};
#pragma unroll
    for (int kb = 0; kb < 2; kb++){
#pragma unroll
      for (int nb = 0; nb < 4; nb++){
        const int row = nb*16 + col;
        const int sl = ((kb*4 + quad) ^ (row & 7)) * 8;
        bf16x8 kf = *(const bf16x8*)&ldsK[cur][row*64 + sl];
        s[nb] = __builtin_amdgcn_mfma_f32_16x16x32_bf16(kb ? qf1 : qf0, kf, s[nb], 0, 0, 0);
      }
    }

    // p = exp2(s + biasL); per-lane row sums
    const bool diag = (j0 == i0);
#pragma unroll
    for (int nb = 0; nb < 4; nb++){
      const int j = j0 + nb*16 + col;
      const float* bp = &ldsBias[irow - j + 63];
#pragma unroll
      for (int r = 0; r < 4; r++){
        float arg = s[nb][r] + bp[r];
        if (diag && (j > irow + r)) arg = -1e9f;
        float p;
        asm volatile("v_exp_f32 %0, %1" : "=v"(p) : "v"(arg));
        s[nb][r] = p;
        lsum[r] += p;
      }
    }

    // P: C-layout -> per-wave LDS -> A-layout (wave-local ordering)
    u16* Pw = ldsP[wid];
#pragma unroll
    for (int nb = 0; nb < 4; nb++)
#pragma unroll
      for (int r = 0; r < 4; r++)
        Pw[(quad*4 + r)*88 + nb*16 + col] = f2bf(s[nb][r]);
    WAITL0;

    // O += P V
#pragma unroll
    for (int kb = 0; kb < 2; kb++){
      bf16x8 pf = *(const bf16x8*)&Pw[col*88 + kb*32 + quad*8];
#pragma unroll
      for (int nb = 0; nb < 4; nb++){
        const int row = nb*16 + col;
        const int sl = ((kb*4 + quad) ^ (row & 7)) * 8;
        bf16x8 vf = *(const bf16x8*)&ldsV[cur][row*64 + sl];
        O[nb] = __builtin_amdgcn_mfma_f32_16x16x32_bf16(pf, vf, O[nb], 0, 0, 0);
      }
    }

    __syncthreads();   // readers done with cur; next KV tile landed (vmcnt 0)
    cur ^= 1;
  }

  // reduce row sums across the 16 cols of each quad
#pragma unroll
  for (int r = 0; r < 4; r++){
    float v = lsum[r];
    v += __shfl_xor(v, 1, 64);
    v += __shfl_xor(v, 2, 64);
    v += __shfl_xor(v, 4, 64);
    v += __shfl_xor(v, 8, 64);
    lsum[r] = v;
  }

  // epilogue: O/l -> Y[(b*T + i)*C + h*64 + d]
#pragma unroll
  for (int nb = 0; nb < 4; nb++){
#pragma unroll
    for (int r = 0; r < 4; r++){
      const int i = irow + r;
      const int d = nb*16 + col;
      Y[((long)(b*T_SEQ + i))*CDIM + h*DHD + d] = f2bf(O[nb][r] / lsum[r]);
    }
  }
}

extern "C" void kernel_launch(void* const* d_in, const int* in_sizes, int n_in,
                              void* d_out, int out_size, void* d_ws, size_t ws_size,
                              hipStream_t stream)
{
  (void)in_sizes; (void)n_in; (void)out_size; (void)ws_size;
  const void* x   = d_in[0];
  const void* Wq  = d_in[1];
  const void* Wk  = d_in[2];
  const void* Wv  = d_in[3];
  const void* Wo  = d_in[4];
  const void* bo  = d_in[5];
  const void* rel = d_in[6];
  // d_in[7] = mask: deterministically causal -> not read

  char* ws = (char*)d_ws;
  const size_t MB = 1024*1024;
  int* flag = (int*)ws;
  char* base = ws + 256;
  u16* WqT = (u16*)(base + 0*MB);
  u16* WkT = (u16*)(base + 2*MB);
  u16* WvT = (u16*)(base + 4*MB);
  u16* Kb  = (u16*)(base + 6*MB);
  u16* VTb = (u16*)(base + 14*MB);    // ..22MB
  u16* Yb  = (u16*)(base + 0*MB);     // phase B: overlaps dead WqT/WkT/WvT
  u16* WoT = (u16*)(base + 8*MB);     // phase B: overlaps dead Kb
  u16* Qb  = (u16*)d_out;             // d_out lower 8MB: Q (overwritten later)
  u16* xbf = Qb + 4u*1024*1024;       // d_out upper 8MB: x as bf16

  dim3 blk(256);
  classify  <<<1, blk, 0, stream>>>((const u32*)x, flag);
  cvt_x     <<<dim3(2048), blk, 0, stream>>>(x, xbf, flag);
  transposeW<<<dim3(16,16,3), blk, 0, stream>>>(Wq, Wk, Wv, WqT, WkT, WvT, flag);
  gemm_qkv  <<<dim3(32,8,3),  blk, 0, stream>>>(xbf, WqT, WkT, WvT, Qb, Kb, VTb);
  attn64    <<<dim3(1024),  blk, 0, stream>>>(Qb, Kb, VTb, rel, Yb, flag);
  transposeW<<<dim3(16,16,1), blk, 0, stream>>>(Wo, Wo, Wo, WoT, WoT, WoT, flag);
  gemm_out  <<<dim3(32,8),    blk, 0, stream>>>(Yb, WoT, bo, d_out, flag);
}

// Round 6
// 216.982 us; speedup vs baseline: 1.2052x; 1.0206x over previous
//
#include <hip/hip_runtime.h>
#include <hip/hip_bf16.h>
#include <stdint.h>

// Self-attention, B=2 T=2048 C=1024 H=16 DH=64, causal + relative bias.
// Round 13: attn64 QK^T computed SWAPPED (S^T = mfma(kf, qf); both fragments
// have identical lane layouts for A/B roles, so only the argument order
// changes). Lane then holds 4 consecutive j for a fixed Q-row i = lane&15:
// the P bounce becomes 4x ds_write_b64 of v_cvt_pk_bf16_f32 pairs (was 16
// scattered ds_write_b16) into the SAME P[i][j] stride-88 layout -> PV read
// side / V path / O epilogue byte-identical. Row-sum is now a single scalar
// per lane (2 shfl_xor + 4 shfl at the end). Softmax/mask/bias re-indexed
// for the S^T layout (same op count; bounds verified). Everything else
// (decomposition, async KV staging, GEMMs) verbatim from round 12.
// Invariants: dual-dtype external loads (flag), ws <= 256B + 22MB.
//
// ws layout (offsets from ws+256, bytes):
//   phase A: WqT @0..2M, WkT @2..4M, WvT @4..6M, K @6..14M, V^T @14..22M
//   phase B (weights/K dead): Y @0..8M, WoT @8..10M
// d_out (16MB): phase A: Q @0..8M, x_bf16 @8..16M; phase B: final f32 out.

#define T_SEQ 2048
#define NH    16
#define DHD   64
#define CDIM  1024

typedef unsigned short u16;
typedef unsigned int   u32;
typedef __attribute__((ext_vector_type(8))) __bf16 bf16x8;   // MFMA A/B operand
typedef __attribute__((ext_vector_type(4))) float f32x4;     // MFMA C/D operand

#define WAITL0   asm volatile("s_waitcnt lgkmcnt(0)" ::: "memory")

__device__ __forceinline__ float bf2f(u16 b){
  union { u32 u; float f; } v; v.u = ((u32)b) << 16; return v.f;
}
__device__ __forceinline__ u16 f2bf(float f){
  union { __bf16 h; u16 u; } v; v.h = (__bf16)f;   // native cvt on gfx950
  return v.u;
}

// async global->LDS, 16B per lane; LDS dest = wave-uniform base + lane*16
__device__ __forceinline__ void gload_lds16(const u16* g, u16* l){
  __builtin_amdgcn_global_load_lds(
      (const __attribute__((address_space(1))) void*)g,
      (__attribute__((address_space(3))) void*)l, 16, 0, 0);
}

// load 8 consecutive elements as packed bf16 (uint4), from bf16 or f32 source
__device__ __forceinline__ uint4 load8(const void* p, long elem, int isbf){
  if (isbf) return *(const uint4*)((const u16*)p + elem);
  const float* fp = (const float*)p + elem;
  float4 a = *(const float4*)fp, b = *(const float4*)(fp + 4);
  uint4 r;
  r.x = (u32)f2bf(a.x) | ((u32)f2bf(a.y) << 16);
  r.y = (u32)f2bf(a.z) | ((u32)f2bf(a.w) << 16);
  r.z = (u32)f2bf(b.x) | ((u32)f2bf(b.y) << 16);
  r.w = (u32)f2bf(b.z) | ((u32)f2bf(b.w) << 16);
  return r;
}
__device__ __forceinline__ float loadf(const void* p, long idx, int isbf){
  return isbf ? bf2f(((const u16*)p)[idx]) : ((const float*)p)[idx];
}

// ---------------- dtype classifier ------------------------------------------
__global__ __launch_bounds__(256) void classify(const u32* __restrict__ x,
                                                int* __restrict__ flag){
  __shared__ int cnt[256];
  int c = 0;
#pragma unroll
  for (int i = 0; i < 16; i++){
    u32 w = x[threadIdx.x * 16 + i];
    int e = (w >> 7) & 0xFF;
    c += (e >= 110 && e <= 140);
  }
  cnt[threadIdx.x] = c;
  __syncthreads();
  for (int s = 128; s > 0; s >>= 1){
    if ((int)threadIdx.x < s) cnt[threadIdx.x] += cnt[threadIdx.x + s];
    __syncthreads();
  }
  if (threadIdx.x == 0) *flag = (cnt[0] > 2048) ? 1 : 0;   // 1 = bf16
}

// ---------------- x -> bf16 (removes per-pass f32 conversion in GEMM) -------
__global__ __launch_bounds__(256) void cvt_x(const void* __restrict__ x,
                                             u16* __restrict__ xbf,
                                             const int* __restrict__ flag){
  const int isbf = *flag;
  const long i = ((long)blockIdx.x * 256 + threadIdx.x) * 8;
  *(uint4*)(xbf + i) = load8(x, i, isbf);
}

// ---------------- weight transpose: out[n][k] = in[k][n], 1024x1024 ----------
__global__ __launch_bounds__(256) void transposeW(
    const void* __restrict__ w0, const void* __restrict__ w1,
    const void* __restrict__ w2,
    u16* __restrict__ o0, u16* __restrict__ o1, u16* __restrict__ o2,
    const int* __restrict__ flag)
{
  __shared__ u16 tile[64][72];
  const int isbf = *flag;
  const int z = blockIdx.z;
  const void* in = z==0 ? w0 : z==1 ? w1 : w2;
  u16*      out  = z==0 ? o0 : z==1 ? o1 : o2;
  const int tid = threadIdx.x;
  const int r0 = blockIdx.y * 64, c0 = blockIdx.x * 64;
  const int rr = tid >> 3;          // 0..31
  const int cc = (tid & 7) * 8;     // 0,8,..,56
#pragma unroll
  for (int rd = 0; rd < 2; rd++){
    int r = rd*32 + rr;
    *(uint4*)&tile[r][cc] = load8(in, (long)(r0 + r)*CDIM + c0 + cc, isbf);
  }
  __syncthreads();
#pragma unroll
  for (int rd = 0; rd < 2; rd++){
    int oc = rd*32 + rr;            // original column offset
    uint4 wv; u32* wp = (u32*)&wv;
#pragma unroll
    for (int t = 0; t < 4; t++){
      u32 lo = tile[cc + 2*t][oc];
      u32 hi = tile[cc + 2*t + 1][oc];
      wp[t] = lo | (hi << 16);
    }
    *(uint4*)(out + (long)(c0 + oc)*CDIM + r0 + cc) = wv;
  }
}

// ---------------- 128x128 GEMM, global_load_lds 2-phase K-loop --------------
// A[M,K] (bf16) @ BT[N,K]^T, K=1024, BK=32, double-buffered 16KB LDS/operand.
// Staging: chunk c = wid*128 + s*64 + lane; LDS slot g'=c&3 of row r=c>>2
// receives SOURCE chunk g'^(r&3) (pre-swizzled source address) -> identical
// LDS image to the old swizzled ds_write path; read side unchanged.
// mode 0: out[m*CDIM+n] + bias (dtype per io_isbf)
// mode 1: out[((b*NH+h)*T+t)*DH+d] bf16 (Q/K; scale applied)
// mode 2: out[((b*NH+h)*DH+d)*T+t] bf16 (V transposed; 8B packed stores)
__device__ __forceinline__ void gemm_body(
    const u16* __restrict__ A, const u16* __restrict__ BT,
    const void* __restrict__ bias, void* __restrict__ out,
    float scale, int mode, int m0, int n0, int io_isbf)
{
  __shared__ u16 ldsA[2][128*32];
  __shared__ u16 ldsB[2][128*32];
  const int tid = threadIdx.x;
  const int wid = tid >> 6, lane = tid & 63;
  const int col = lane & 15, quad = lane >> 4;
  const int wm = (wid >> 1) * 64, wn = (wid & 1) * 64;

  // per-lane pre-swizzled source offsets for the two 64-chunk instructions
  const int c0 = wid*128 + lane, c1 = c0 + 64;
  const int r0c = c0 >> 2, g0c = c0 & 3;
  const int r1c = c1 >> 2, g1c = c1 & 3;
  const long aoff0 = (long)r0c*CDIM + ((g0c ^ (r0c & 3)) << 3);
  const long aoff1 = (long)r1c*CDIM + ((g1c ^ (r1c & 3)) << 3);
  const int lds0 = (wid*128)*8;          // u16 elems; HW adds lane*16B
  const int lds1 = (wid*128 + 64)*8;

  const u16* gA = A  + (long)m0*CDIM;
  const u16* gB = BT + (long)n0*CDIM;

  auto stage = [&](int buf, int k0){
    gload_lds16(gA + k0 + aoff0, &ldsA[buf][lds0]);
    gload_lds16(gA + k0 + aoff1, &ldsA[buf][lds1]);
    gload_lds16(gB + k0 + aoff0, &ldsB[buf][lds0]);
    gload_lds16(gB + k0 + aoff1, &ldsB[buf][lds1]);
  };

  f32x4 acc[4][4] = {};
  const int NK = CDIM / 32;

  stage(0, 0);
  __syncthreads();            // vmcnt(0) drain: tile 0 visible

  int cur = 0;
  for (int k = 0; k < NK; k++){
    if (k + 1 < NK) stage(cur ^ 1, (k + 1) * 32);   // async into other buffer

    bf16x8 af[4], bfr[4];
#pragma unroll
    for (int mi = 0; mi < 4; mi++){
      const int r = wm + mi*16 + col;
      af[mi] = *(const bf16x8*)&ldsA[cur][r*32 + ((quad ^ (r & 3)) * 8)];
    }
#pragma unroll
    for (int ni = 0; ni < 4; ni++){
      const int r = wn + ni*16 + col;
      bfr[ni] = *(const bf16x8*)&ldsB[cur][r*32 + ((quad ^ (r & 3)) * 8)];
    }
#pragma unroll
    for (int mi = 0; mi < 4; mi++)
#pragma unroll
      for (int ni = 0; ni < 4; ni++)
        acc[mi][ni] = __builtin_amdgcn_mfma_f32_16x16x32_bf16(af[mi], bfr[ni], acc[mi][ni], 0, 0, 0);

    __syncthreads();          // readers done with cur; next tile landed
    cur ^= 1;
  }

  // epilogue
  if (mode == 2){
#pragma unroll
    for (int ni = 0; ni < 4; ni++){
      const int n = n0 + wn + ni*16 + col;
      const int h = n >> 6, d = n & 63;
#pragma unroll
      for (int mi = 0; mi < 4; mi++){
        const int m = m0 + wm + mi*16 + quad*4;
        const int b = m >> 11, t = m & (T_SEQ-1);
        uint2 pk;
        pk.x = (u32)f2bf(acc[mi][ni][0]) | ((u32)f2bf(acc[mi][ni][1]) << 16);
        pk.y = (u32)f2bf(acc[mi][ni][2]) | ((u32)f2bf(acc[mi][ni][3]) << 16);
        *(uint2*)((u16*)out + ((long)(b*NH + h)*DHD + d)*T_SEQ + t) = pk;
      }
    }
  } else {
#pragma unroll
    for (int ni = 0; ni < 4; ni++){
      const int n = n0 + wn + ni*16 + col;
      const float bv = bias ? loadf(bias, n, io_isbf) : 0.f;
#pragma unroll
      for (int mi = 0; mi < 4; mi++){
#pragma unroll
        for (int r = 0; r < 4; r++){
          const int m = m0 + wm + mi*16 + quad*4 + r;
          const float v = acc[mi][ni][r] * scale + bv;
          if (mode == 0){
            const long idx = (long)m*CDIM + n;
            if (io_isbf) ((u16*)out)[idx] = f2bf(v);
            else         ((float*)out)[idx] = v;
          } else {
            const int b = m >> 11, t = m & (T_SEQ-1), h = n >> 6, d = n & 63;
            ((u16*)out)[((long)(b*NH + h)*T_SEQ + t)*DHD + d] = f2bf(v);
          }
        }
      }
    }
  }
}

__global__ __launch_bounds__(256) void gemm_qkv(
    const u16* __restrict__ xbf,
    const u16* __restrict__ WqT, const u16* __restrict__ WkT, const u16* __restrict__ WvT,
    u16* __restrict__ Qb, u16* __restrict__ Kb, u16* __restrict__ VTb)
{
  const int z = blockIdx.z;
  const u16* BT = z==0 ? WqT : z==1 ? WkT : WvT;
  u16*      dst = z==0 ? Qb  : z==1 ? Kb  : VTb;
  // Q: fold DH^-0.5 and log2(e) so attention exp is a bare v_exp_f32
  const float scale = (z==0) ? 0.125f * 1.44269504f : 1.0f;
  const int mode = (z==2) ? 2 : 1;
  gemm_body(xbf, BT, nullptr, dst, scale, mode, blockIdx.x*128, blockIdx.y*128, 1);
}

__global__ __launch_bounds__(256) void gemm_out(
    const u16* __restrict__ Y, const u16* __restrict__ WoT,
    const void* __restrict__ bo, void* __restrict__ out,
    const int* __restrict__ flag)
{
  gemm_body(Y, WoT, bo, out, 1.0f, 0, blockIdx.x*128, blockIdx.y*128, *flag);
}

// ---------------- flash attention, one 64-row Q-tile per block --------------
// 1024 blocks = 8 XCDs x 4 heads x 32 tiles; ti in balanced quartets; K/V
// async-staged (double buffer, pre-swizzled source). QK^T computed swapped:
// S^T = mfma(kf, qf) -> lane holds i = i0+wid*16+(lane&15), j = j0 + nb*16 +
// quad*4 + r. P pack: per nb, two v_cvt_pk_bf16_f32 + one ds_write_b64 into
// the same P[i][j] stride-88 image -> PV read side unchanged. Row sum is one
// scalar/lane; final reduce via 2 shfl_xor + 4 shfl.
__global__ __launch_bounds__(256) void attn64(
    const u16* __restrict__ Q, const u16* __restrict__ K, const u16* __restrict__ VT,
    const void* __restrict__ rel, u16* __restrict__ Y,
    const int* __restrict__ flag)
{
  __shared__ u16 ldsK[2][64*64];
  __shared__ u16 ldsV[2][64*64];
  __shared__ u16 ldsP[4][16*88];    // per-wave P[i][j], row stride 88
  __shared__ float ldsBias[2112];   // biasL[d+63], d = i-j

  const int isbf = *flag;
  const int tid = threadIdx.x, wid = tid >> 6, lane = tid & 63;
  const int col = lane & 15, quad = lane >> 4;

  const int l = (int)blockIdx.x;
  const int xcd = l & 7, s = l >> 3;        // s in [0,128)
  const int bh = xcd * 4 + (s & 3);
  const int g = s >> 2, gq = g >> 3, g0 = g & 7;   // g in [0,32)
  const int ti = (gq == 0) ? 31 - g0
               : (gq == 1) ? g0
               : (gq == 2) ? 23 - g0
                           : 8 + g0;
  const int i0 = ti * 64;

  const int h = bh & (NH - 1);
  const int b = bh >> 4;

  const u16* Qh = Q  + (long)bh * T_SEQ * DHD;
  const u16* Kh = K  + (long)bh * T_SEQ * DHD;
  const u16* Vh = VT + (long)bh * DHD * T_SEQ;
  const long relbase = (long)h * (2*T_SEQ - 1) + (T_SEQ - 1);
  const float MLOG = 16.0f * 1.44269504f;

  // async staging map: wave w covers chunks c = w*64+lane and 256 + w*64+lane
  // (row = c>>3, slot = c&7); source chunk = slot^(row&7) (involution), so
  // the LDS image matches the old swizzled ds_write path exactly.
  const int srow0 = wid*8 + (lane >> 3);          // rows 0..31
  const int srow1 = srow0 + 32;                   // rows 32..63
  const int soff  = ((lane & 7) ^ ((lane >> 3) & 7)) * 8;  // swizzled src col
  const int sb0   = wid*512;                      // u16; HW adds lane*16B
  const int sb1   = 2048 + wid*512;

  auto stage = [&](int buf, int j0){
    gload_lds16(Kh + (long)(j0 + srow0)*DHD + soff, &ldsK[buf][sb0]);
    gload_lds16(Kh + (long)(j0 + srow1)*DHD + soff, &ldsK[buf][sb1]);
    gload_lds16(Vh + (long)srow0*T_SEQ + j0 + soff, &ldsV[buf][sb0]);
    gload_lds16(Vh + (long)srow1*T_SEQ + j0 + soff, &ldsV[buf][sb1]);
  };

  // stage biasL for d in [-63, i0+63]
  const int nbias = i0 + 127;
  for (int t = tid; t < nbias; t += 256)
    ldsBias[t] = loadf(rel, relbase + t - 63, isbf) * 1.44269504f - MLOG;

  bf16x8 qf0, qf1;   // fragment: row i0+wid*16+col, k = kb*32+quad*8+j
  {
    const u16* qp = Qh + (long)(i0 + wid*16 + col)*DHD + quad*8;
    qf0 = *(const bf16x8*)qp;
    qf1 = *(const bf16x8*)(qp + 32);
  }

  f32x4 O[4] = {};
  float lsumv = 0.f;                        // row-sum for Q row icol
  const int icol = i0 + wid*16 + col;       // this lane's Q row (S^T layout)
  const int irow = i0 + wid*16 + quad*4;    // O-epilogue rows (unchanged)

  stage(0, 0);
  __syncthreads();   // vmcnt+lgkm drain: KV tile 0 + bias visible

  int cur = 0;
  for (int j0 = 0; j0 <= i0; j0 += 64){
    const bool have_next = (j0 + 64 <= i0);
    if (have_next) stage(cur ^ 1, j0 + 64);   // async into other buffer

    // S^T = K Q^T : lane holds i = icol, j = j0 + nb*16 + quad*4 + r
    f32x4 sv[4] = {};
#pragma unroll
    for (int kb = 0; kb < 2; kb++){
#pragma unroll
      for (int nb = 0; nb < 4; nb++){
        const int row = nb*16 + col;
        const int sl = ((kb*4 + quad) ^ (row & 7)) * 8;
        bf16x8 kf = *(const bf16x8*)&ldsK[cur][row*64 + sl];
        sv[nb] = __builtin_amdgcn_mfma_f32_16x16x32_bf16(kf, kb ? qf1 : qf0, sv[nb], 0, 0, 0);
      }
    }

    // p = exp2(s + biasL); bias index d = icol - j, j = j0+nb*16+quad*4+r
    const bool diag = (j0 == i0);
#pragma unroll
    for (int nb = 0; nb < 4; nb++){
      const float* bp = &ldsBias[icol - j0 - nb*16 - quad*4 + 63];
#pragma unroll
      for (int r = 0; r < 4; r++){
        float arg = sv[nb][r] + bp[-r];
        if (diag && (nb*16 + quad*4 + r > wid*16 + col)) arg = -1e9f;
        float p;
        asm volatile("v_exp_f32 %0, %1" : "=v"(p) : "v"(arg));
        sv[nb][r] = p;
        lsumv += p;
      }
    }

    // P pack: 4 consecutive j per nb -> 2 cvt_pk + 1 b64 store (P[i][j], i=col)
    u16* Pw = ldsP[wid];
#pragma unroll
    for (int nb = 0; nb < 4; nb++){
      u32 lo, hi;
      asm("v_cvt_pk_bf16_f32 %0, %1, %2" : "=v"(lo) : "v"(sv[nb][0]), "v"(sv[nb][1]));
      asm("v_cvt_pk_bf16_f32 %0, %1, %2" : "=v"(hi) : "v"(sv[nb][2]), "v"(sv[nb][3]));
      uint2 pk; pk.x = lo; pk.y = hi;
      *(uint2*)&Pw[col*88 + nb*16 + quad*4] = pk;
    }
    WAITL0;

    // O += P V  (read side identical to previous rounds)
#pragma unroll
    for (int kb = 0; kb < 2; kb++){
      bf16x8 pf = *(const bf16x8*)&Pw[col*88 + kb*32 + quad*8];
#pragma unroll
      for (int nb = 0; nb < 4; nb++){
        const int row = nb*16 + col;
        const int sl = ((kb*4 + quad) ^ (row & 7)) * 8;
        bf16x8 vf = *(const bf16x8*)&ldsV[cur][row*64 + sl];
        O[nb] = __builtin_amdgcn_mfma_f32_16x16x32_bf16(pf, vf, O[nb], 0, 0, 0);
      }
    }

    __syncthreads();   // readers done with cur; next KV tile landed (vmcnt 0)
    cur ^= 1;
  }

  // reduce row sums: quads of same col hold partial sums of row icol
  lsumv += __shfl_xor(lsumv, 16, 64);
  lsumv += __shfl_xor(lsumv, 32, 64);
  // redistribute: epilogue lane needs rows irow+r (r=0..3) = col' = quad*4+r
  float rs[4];
#pragma unroll
  for (int r = 0; r < 4; r++)
    rs[r] = __shfl(lsumv, quad*4 + r, 16);

  // epilogue: O/l -> Y[(b*T + i)*C + h*64 + d]
#pragma unroll
  for (int nb = 0; nb < 4; nb++){
#pragma unroll
    for (int r = 0; r < 4; r++){
      const int i = irow + r;
      const int d = nb*16 + col;
      Y[((long)(b*T_SEQ + i))*CDIM + h*DHD + d] = f2bf(O[nb][r] / rs[r]);
    }
  }
}

extern "C" void kernel_launch(void* const* d_in, const int* in_sizes, int n_in,
                              void* d_out, int out_size, void* d_ws, size_t ws_size,
                              hipStream_t stream)
{
  (void)in_sizes; (void)n_in; (void)out_size; (void)ws_size;
  const void* x   = d_in[0];
  const void* Wq  = d_in[1];
  const void* Wk  = d_in[2];
  const void* Wv  = d_in[3];
  const void* Wo  = d_in[4];
  const void* bo  = d_in[5];
  const void* rel = d_in[6];
  // d_in[7] = mask: deterministically causal -> not read

  char* ws = (char*)d_ws;
  const size_t MB = 1024*1024;
  int* flag = (int*)ws;
  char* base = ws + 256;
  u16* WqT = (u16*)(base + 0*MB);
  u16* WkT = (u16*)(base + 2*MB);
  u16* WvT = (u16*)(base + 4*MB);
  u16* Kb  = (u16*)(base + 6*MB);
  u16* VTb = (u16*)(base + 14*MB);    // ..22MB
  u16* Yb  = (u16*)(base + 0*MB);     // phase B: overlaps dead WqT/WkT/WvT
  u16* WoT = (u16*)(base + 8*MB);     // phase B: overlaps dead Kb
  u16* Qb  = (u16*)d_out;             // d_out lower 8MB: Q (overwritten later)
  u16* xbf = Qb + 4u*1024*1024;       // d_out upper 8MB: x as bf16

  dim3 blk(256);
  classify  <<<1, blk, 0, stream>>>((const u32*)x, flag);
  cvt_x     <<<dim3(2048), blk, 0, stream>>>(x, xbf, flag);
  transposeW<<<dim3(16,16,3), blk, 0, stream>>>(Wq, Wk, Wv, WqT, WkT, WvT, flag);
  gemm_qkv  <<<dim3(32,8,3),  blk, 0, stream>>>(xbf, WqT, WkT, WvT, Qb, Kb, VTb);
  attn64    <<<dim3(1024),  blk, 0, stream>>>(Qb, Kb, VTb, rel, Yb, flag);
  transposeW<<<dim3(16,16,1), blk, 0, stream>>>(Wo, Wo, Wo, WoT, WoT, WoT, flag);
  gemm_out  <<<dim3(32,8),    blk, 0, stream>>>(Yb, WoT, bo, d_out, flag);
}